// Round 8
// baseline (790.840 us; speedup 1.0000x reference)
//
#include <hip/hip_runtime.h>
#include <math.h>
#include <float.h>

#define NNODES 50000
#define NPAD   50048   // 782*64, rows the MFMA gemm may touch
#define NEDGES 800000
#define CHUNK  196     // per-block scan chunk: 256*196 = 50176 >= NNODES
#define PREPB  256     // prep grid: 256 blocks x 1024 thr = 1 block/CU (resident)
// D = 128 fixed

typedef __attribute__((ext_vector_type(8))) short bfrag;   // 8 bf16 (4 VGPR)
typedef __attribute__((ext_vector_type(4))) float ffrag;   // 4 fp32 acc

// ---------------------------------------------------------------- bf16 split
// v ~= hi + lo, both RN-bf16. |v - hi - lo| <~ 2^-17 |v|.
static __device__ __forceinline__ void bsplit(float f, ushort& h, ushort& l) {
  unsigned u = __float_as_uint(f);
  unsigned hb = (u + 0x7FFFu + ((u >> 16) & 1u)) >> 16;
  h = (ushort)hb;
  float r = f - __uint_as_float(hb << 16);
  unsigned v = __float_as_uint(r);
  l = (ushort)((v + 0x7FFFu + ((v >> 16) & 1u)) >> 16);
}

// --------------------------------------------------------- soft grid barrier
// Valid because grid = 256 blocks of 1024 thr, 1/CU, all co-resident.
// bar zeroed by hipMemsetAsync before launch; barrier k waits for k*PREPB.
static __device__ __forceinline__ void gbar(int* bar, int target) {
  __threadfence();
  __syncthreads();
  if (threadIdx.x == 0) {
    atomicAdd(bar, 1);
    while (__hip_atomic_load(bar, __ATOMIC_ACQUIRE,
                             __HIP_MEMORY_SCOPE_AGENT) < target)
      __builtin_amdgcn_s_sleep(8);
  }
  __syncthreads();
}

// ------------------------------------------------------- fused prep kernel
// P0: W->bf16 planes, x->bf16 planes, dst histogram (counts pre-zeroed by
//     memset). BAR. P1: per-block scan of (counts+1). BAR. P2: block0 scans
//     block sums. BAR. P3: rowptr/cursor. BAR. P4: CSR scatter.
__global__ __launch_bounds__(1024, 4) void prep_kernel(
    const float* __restrict__ x, const int* __restrict__ ei,
    const float* __restrict__ w0, const float* __restrict__ w1,
    const float* __restrict__ w2, const float* __restrict__ w3,
    const float* __restrict__ w4, const float* __restrict__ w5,
    ushort* __restrict__ bhi, ushort* __restrict__ blo,
    ushort* __restrict__ ahi, ushort* __restrict__ alo,
    int* __restrict__ counts, int* __restrict__ part,
    int* __restrict__ bsum, int* __restrict__ bsx,
    int* __restrict__ rowptr, int* __restrict__ cursor,
    int* __restrict__ col, int* __restrict__ bar)
{
  const int t = threadIdx.x;
  const int gid = blockIdx.x * 1024 + t;
  const int gstride = PREPB * 1024;
  __shared__ int sh[256];

  // ---- P0a: weights -> bf16 hi/lo planes (rows: Wl then Wr per layer)
  for (int g = gid; g < 6 * 16384; g += gstride) {
    int mat = g >> 14;
    int r = g & 16383;
    const float* s = w0;
    if (mat == 1) s = w1; else if (mat == 2) s = w2; else if (mat == 3) s = w3;
    else if (mat == 4) s = w4; else if (mat == 5) s = w5;
    ushort h, l;
    bsplit(s[r], h, l);
    int o = (mat >> 1) * 32768 + (mat & 1) * 16384 + r;
    bhi[o] = h;
    blo[o] = l;
  }
  // ---- P0b: x -> bf16 hi/lo planes
  for (int idx = gid; idx < NNODES * 32; idx += gstride) {
    float4 v = ((const float4*)x)[idx];
    ushort h0,l0,h1,l1,h2,l2,h3,l3;
    bsplit(v.x, h0, l0); bsplit(v.y, h1, l1);
    bsplit(v.z, h2, l2); bsplit(v.w, h3, l3);
    ushort4 hv = {h0, h1, h2, h3};
    ushort4 lv = {l0, l1, l2, l3};
    ((ushort4*)ahi)[idx] = hv;
    ((ushort4*)alo)[idx] = lv;
  }
  // ---- P0c: dst histogram
  for (int e = gid; e < NEDGES; e += gstride)
    atomicAdd(&counts[ei[NEDGES + e]], 1);

  gbar(bar, 1 * PREPB);

  // ---- P1: per-block exclusive scan of (counts[i]+1) over CHUNK elems
  {
    int base = blockIdx.x * CHUNK;
    int v = 0;
    if (t < 256) {
      int idx = base + t;
      v = (t < CHUNK && idx < NNODES) ? counts[idx] + 1 : 0;
      sh[t] = v;
    }
    __syncthreads();
    for (int off = 1; off < 256; off <<= 1) {
      int u = 0;
      if (t < 256 && t >= off) u = sh[t - off];
      __syncthreads();
      if (t < 256 && t >= off) sh[t] += u;
      __syncthreads();
    }
    if (t < CHUNK && base + t < NNODES) part[base + t] = sh[t] - v;
    if (t == 255) bsum[blockIdx.x] = sh[255];
  }

  gbar(bar, 2 * PREPB);

  // ---- P2: block 0 scans the 256 block sums (exclusive)
  if (blockIdx.x == 0) {
    int v = 0;
    if (t < 256) { v = bsum[t]; sh[t] = v; }
    __syncthreads();
    for (int off = 1; off < 256; off <<= 1) {
      int u = 0;
      if (t < 256 && t >= off) u = sh[t - off];
      __syncthreads();
      if (t < 256 && t >= off) sh[t] += u;
      __syncthreads();
    }
    if (t < 256) bsx[t] = sh[t] - v;
  }

  gbar(bar, 3 * PREPB);

  // ---- P3: rowptr = part + block offset; init cursor
  for (int i = gid; i < NNODES; i += gstride) {
    int r = part[i] + bsx[i / CHUNK];
    rowptr[i] = r;
    cursor[i] = r;
  }
  if (gid == 0) rowptr[NNODES] = NEDGES + NNODES;

  gbar(bar, 4 * PREPB);

  // ---- P4: CSR scatter (self loops appended)
  for (int e = gid; e < NEDGES + NNODES; e += gstride) {
    int s, d;
    if (e < NEDGES) { s = ei[e]; d = ei[NEDGES + e]; }
    else           { s = e - NEDGES; d = s; }
    int slot = atomicAdd(&cursor[d], 1);
    col[slot] = s;
  }
}

// ------------------------------------------------- MFMA split-bf16 dual GEMM
// xl[m][n] = sum_k h[m][k] Wl[n][k]; xr likewise; one M x 256 GEMM with
// B = [Wl ; Wr], C = Ah.Bh + Ah.Bl + Al.Bh (fp32 acc, Al.Bl dropped).
__global__ __launch_bounds__(256) void gemm_mfma(
    const ushort* __restrict__ ahi, const ushort* __restrict__ alo,
    const ushort* __restrict__ bhi, const ushort* __restrict__ blo,
    float* __restrict__ xl, float* __restrict__ xr)
{
  const int wave = threadIdx.x >> 6;
  const int lane = threadIdx.x & 63;
  const int l16  = lane & 15;
  const int kq   = lane >> 4;              // 0..3
  const int m0   = blockIdx.x * 64;

  ffrag acc[4][4];
#pragma unroll
  for (int mt = 0; mt < 4; ++mt)
#pragma unroll
    for (int nt = 0; nt < 4; ++nt)
      acc[mt][nt] = (ffrag){0.f, 0.f, 0.f, 0.f};

#pragma unroll
  for (int kb = 0; kb < 4; ++kb) {
    const int k0 = kb * 32 + kq * 8;
    bfrag ah[4], al[4], bh[4], bl[4];
#pragma unroll
    for (int mt = 0; mt < 4; ++mt) {
      int m = m0 + mt * 16 + l16;          // < NPAD (planes padded)
      ah[mt] = *(const bfrag*)&ahi[m * 128 + k0];
      al[mt] = *(const bfrag*)&alo[m * 128 + k0];
    }
#pragma unroll
    for (int nt = 0; nt < 4; ++nt) {
      int n = wave * 64 + nt * 16 + l16;   // 0..255
      bh[nt] = *(const bfrag*)&bhi[n * 128 + k0];
      bl[nt] = *(const bfrag*)&blo[n * 128 + k0];
    }
#pragma unroll
    for (int mt = 0; mt < 4; ++mt)
#pragma unroll
      for (int nt = 0; nt < 4; ++nt) {
        acc[mt][nt] = __builtin_amdgcn_mfma_f32_16x16x32_bf16(
            ah[mt], bh[nt], acc[mt][nt], 0, 0, 0);
        acc[mt][nt] = __builtin_amdgcn_mfma_f32_16x16x32_bf16(
            ah[mt], bl[nt], acc[mt][nt], 0, 0, 0);
        acc[mt][nt] = __builtin_amdgcn_mfma_f32_16x16x32_bf16(
            al[mt], bh[nt], acc[mt][nt], 0, 0, 0);
      }
  }

#pragma unroll
  for (int mt = 0; mt < 4; ++mt) {
    int mb = m0 + mt * 16 + kq * 4;
#pragma unroll
    for (int nt = 0; nt < 4; ++nt) {
      int ng = wave * 64 + nt * 16 + l16;
      float* dst = (ng < 128) ? xl : xr;
      int n = ng & 127;
#pragma unroll
      for (int r = 0; r < 4; ++r) {
        int m = mb + r;
        if (m < NNODES) dst[m * 128 + n] = acc[mt][nt][r];
      }
    }
  }
}

// ---------------------------------------- fused attention + aggregate + GELU
// One wave per dst node, two 32-lane halves, each half 2 edges/iter with
// inline masking (only the 2nd edge of a pair can be invalid).
// Logit algebra: leaky(t)=0.6t+0.4|t| and the per-dst 0.6*att.xr shift
// cancels in softmax, so q = 0.4L*att.|v+xr| + 0.6L*att.v in base-2
// (L=log2 e, folded into two scaled copies of att -> exp2f, no range mul).
// Deferred-max: single per-half reference m2, rescale only if q > m2+86
// (2^86 ~ 7.7e25; sums stay far below fp32 max). One exp per edge.
__global__ __launch_bounds__(256) void agg_kernel(
    const int* __restrict__ rowptr, const int* __restrict__ col,
    const float* __restrict__ xl, const float* __restrict__ xr,
    const float* __restrict__ att, const float* __restrict__ bias,
    float* __restrict__ hout, ushort* __restrict__ ahi,
    ushort* __restrict__ alo, int last)
{
  const int tid  = threadIdx.x;
  const int lane = tid & 63;
  const int half = lane >> 5;
  const int l32  = lane & 31;
  const int d    = blockIdx.x * 4 + (tid >> 6);

  const float4* xl4 = (const float4*)xl;
  float4 xrv = ((const float4*)xr)[d * 32 + l32];
  float4 avr = ((const float4*)att)[l32];
  const float CA = 0.4f * 1.4426950408889634f;
  const float CP = 0.6f * 1.4426950408889634f;
  float4 avA, avP;
  avA.x = avr.x * CA; avA.y = avr.y * CA; avA.z = avr.z * CA; avA.w = avr.w * CA;
  avP.x = avr.x * CP; avP.y = avr.y * CP; avP.z = avr.z * CP; avP.w = avr.w * CP;
  int beg = rowptr[d], end = rowptr[d + 1];

  float m2 = -1e30f;                      // finite sentinel (not -inf)
  float dn0 = 0.f, dn1 = 0.f;
  float4 a0 = {0.f,0.f,0.f,0.f}, a1 = {0.f,0.f,0.f,0.f};

  for (int k0 = beg + 2 * half; k0 < end; k0 += 4) {
    int kb = k0 + 1;                      // k0 always valid; kb maybe not
    bool vb = kb < end;
    int ca = col[k0];
    int cb = col[vb ? kb : beg];
    float4 va = xl4[ca * 32 + l32];
    float4 vB = xl4[cb * 32 + l32];

    float4 ta, tb;
    ta.x = va.x + xrv.x; ta.y = va.y + xrv.y; ta.z = va.z + xrv.z; ta.w = va.w + xrv.w;
    tb.x = vB.x + xrv.x; tb.y = vB.y + xrv.y; tb.z = vB.z + xrv.z; tb.w = vB.w + xrv.w;

    float qa = fmaf(avA.x, fabsf(ta.x), avP.x * va.x);
    qa = fmaf(avA.y, fabsf(ta.y), fmaf(avP.y, va.y, qa));
    qa = fmaf(avA.z, fabsf(ta.z), fmaf(avP.z, va.z, qa));
    qa = fmaf(avA.w, fabsf(ta.w), fmaf(avP.w, va.w, qa));
    float qb = fmaf(avA.x, fabsf(tb.x), avP.x * vB.x);
    qb = fmaf(avA.y, fabsf(tb.y), fmaf(avP.y, vB.y, qb));
    qb = fmaf(avA.z, fabsf(tb.z), fmaf(avP.z, vB.z, qb));
    qb = fmaf(avA.w, fabsf(tb.w), fmaf(avP.w, vB.w, qb));
#pragma unroll
    for (int off = 16; off > 0; off >>= 1) {   // 2 independent chains
      qa += __shfl_xor(qa, off, 64);
      qb += __shfl_xor(qb, off, 64);
    }
    if (!vb) qb = -FLT_MAX;               // exp2(qb-m2) -> 0
    float qm = fmaxf(qa, qb);
    if (qm > m2 + 86.f) {                 // first iter + rare outliers
      float sc = exp2f(m2 - qm);          // m2=-1e30 -> 0: zeroes zeros
      dn0 *= sc; dn1 *= sc;
      a0.x *= sc; a0.y *= sc; a0.z *= sc; a0.w *= sc;
      a1.x *= sc; a1.y *= sc; a1.z *= sc; a1.w *= sc;
      m2 = qm;
    }
    float wa = exp2f(qa - m2);
    float wb = exp2f(qb - m2);
    dn0 += wa; dn1 += wb;
    a0.x = fmaf(wa, va.x, a0.x); a0.y = fmaf(wa, va.y, a0.y);
    a0.z = fmaf(wa, va.z, a0.z); a0.w = fmaf(wa, va.w, a0.w);
    a1.x = fmaf(wb, vB.x, a1.x); a1.y = fmaf(wb, vB.y, a1.y);
    a1.z = fmaf(wb, vB.z, a1.z); a1.w = fmaf(wb, vB.w, a1.w);
  }

  // intra-half states share m2 -> plain adds
  float dn = dn0 + dn1;
  float4 ac;
  ac.x = a0.x + a1.x; ac.y = a0.y + a1.y;
  ac.z = a0.z + a1.z; ac.w = a0.w + a1.w;

  // merge across halves; empty half has m2=-1e30 -> weight 0
  float Mo  = __shfl_xor(m2, 32, 64);
  float dno = __shfl_xor(dn, 32, 64);
  float aox = __shfl_xor(ac.x, 32, 64);
  float aoy = __shfl_xor(ac.y, 32, 64);
  float aoz = __shfl_xor(ac.z, 32, 64);
  float aow = __shfl_xor(ac.w, 32, 64);
  float M  = fmaxf(m2, Mo);
  float eA = exp2f(m2 - M), eB = exp2f(Mo - M);
  float den = dn * eA + dno * eB;
  float inv = 1.f / den;
  float4 bi = ((const float4*)bias)[l32];
  float o0 = fmaf((ac.x * eA + aox * eB), inv, bi.x);
  float o1 = fmaf((ac.y * eA + aoy * eB), inv, bi.y);
  float o2 = fmaf((ac.z * eA + aoz * eB), inv, bi.z);
  float o3 = fmaf((ac.w * eA + aow * eB), inv, bi.w);
  o0 = 0.5f * o0 * (1.f + erff(o0 * 0.70710678118654752f));
  o1 = 0.5f * o1 * (1.f + erff(o1 * 0.70710678118654752f));
  o2 = 0.5f * o2 * (1.f + erff(o2 * 0.70710678118654752f));
  o3 = 0.5f * o3 * (1.f + erff(o3 * 0.70710678118654752f));
  if (half == 0) {
    if (last) {
      ((float4*)hout)[d * 32 + l32] = make_float4(o0, o1, o2, o3);
    } else {
      ushort h0,l0,h1,l1,h2,l2,h3,l3;
      bsplit(o0, h0, l0); bsplit(o1, h1, l1);
      bsplit(o2, h2, l2); bsplit(o3, h3, l3);
      ushort4 hv = {h0, h1, h2, h3};
      ushort4 lv = {l0, l1, l2, l3};
      ((ushort4*)ahi)[d * 32 + l32] = hv;
      ((ushort4*)alo)[d * 32 + l32] = lv;
    }
  }
}

// ------------------------------------------------------------------ launch
extern "C" void kernel_launch(void* const* d_in, const int* in_sizes, int n_in,
                              void* d_out, int out_size, void* d_ws, size_t ws_size,
                              hipStream_t stream)
{
  const float* x = (const float*)d_in[0];
  const int* ei = (const int*)d_in[1];     // int inputs arrive as int32
  const float *Wl[3], *Wr[3], *attv[3], *bv[3];
  for (int l = 0; l < 3; ++l) {
    Wl[l]   = (const float*)d_in[2 + 4 * l];
    Wr[l]   = (const float*)d_in[3 + 4 * l];
    attv[l] = (const float*)d_in[4 + 4 * l];
    bv[l]   = (const float*)d_in[5 + 4 * l];
  }

  char* base = (char*)d_ws;
  size_t off = 0;
  auto alloc = [&](size_t bytes) -> char* {
    char* p = base + off;
    off += (bytes + 255) & ~(size_t)255;
    return p;
  };
  int* bar     = (int*)alloc(256);                          // zeroed w/ counts
  int* counts  = (int*)alloc((size_t)NNODES * 4);
  ushort* ahi  = (ushort*)alloc((size_t)NPAD * 128 * 2);    // 12.8 MB
  ushort* alo  = (ushort*)alloc((size_t)NPAD * 128 * 2);
  ushort* bhi  = (ushort*)alloc((size_t)3 * 256 * 128 * 2); // 196 KB
  ushort* blo  = (ushort*)alloc((size_t)3 * 256 * 128 * 2);
  float* xl    = (float*)alloc((size_t)NNODES * 128 * 4);   // 25.6 MB
  int* rowptr  = (int*)alloc((size_t)(NNODES + 1) * 4);
  int* cursor  = (int*)alloc((size_t)NNODES * 4);
  int* part    = (int*)alloc((size_t)(PREPB * CHUNK) * 4);
  int* bsum    = (int*)alloc((size_t)256 * 4);
  int* bsx     = (int*)alloc((size_t)256 * 4);
  int* col     = (int*)alloc((size_t)(NEDGES + NNODES) * 4);
  float* xr    = (float*)d_out;   // aliased: agg wave reads its xr row before
                                  // writing the same row; no cross-row hazard.
  (void)ws_size; (void)in_sizes; (void)n_in; (void)out_size;

  // bar + counts are adjacent: one memset zeroes both (bar MUST be 0 for the
  // soft grid barrier's absolute targets).
  (void)hipMemsetAsync(bar, 0, 256 + (size_t)NNODES * 4, stream);
  prep_kernel<<<PREPB, 1024, 0, stream>>>(
      x, ei, Wl[0], Wr[0], Wl[1], Wr[1], Wl[2], Wr[2],
      bhi, blo, ahi, alo, counts, part, bsum, bsx, rowptr, cursor, col, bar);

  for (int l = 0; l < 3; ++l) {
    gemm_mfma<<<NPAD / 64, 256, 0, stream>>>(
        ahi, alo, bhi + (size_t)l * 32768, blo + (size_t)l * 32768, xl, xr);
    agg_kernel<<<NNODES / 4, 256, 0, stream>>>(
        rowptr, col, xl, xr, attv[l], bv[l], (float*)d_out, ahi, alo,
        (l == 2) ? 1 : 0);
  }
}

// Round 9
// 512.616 us; speedup vs baseline: 1.5428x; 1.5428x over previous
//
#include <hip/hip_runtime.h>
#include <math.h>
#include <float.h>

#define NNODES 50000
#define NPAD   50048   // 782*64, rows the MFMA gemm may touch
#define NEDGES 800000
#define NBLK 196       // ceil(50000/256)
// D = 128 fixed

typedef __attribute__((ext_vector_type(8))) short bfrag;   // 8 bf16 (4 VGPR)
typedef __attribute__((ext_vector_type(4))) float ffrag;   // 4 fp32 acc

// ---------------------------------------------------------------- bf16 split
// v ~= hi + lo, both RN-bf16. |v - hi - lo| <~ 2^-17 |v|.
static __device__ __forceinline__ void bsplit(float f, ushort& h, ushort& l) {
  unsigned u = __float_as_uint(f);
  unsigned hb = (u + 0x7FFFu + ((u >> 16) & 1u)) >> 16;
  h = (ushort)hb;
  float r = f - __uint_as_float(hb << 16);
  unsigned v = __float_as_uint(r);
  l = (ushort)((v + 0x7FFFu + ((v >> 16) & 1u)) >> 16);
}

// --------------------------------- prep0: W->bf16, x->bf16, hist (no deps!)
// Barrier-free fusion of three independent stages; normal occupancy.
__global__ __launch_bounds__(256) void prep0_kernel(
    const float* __restrict__ x, const int* __restrict__ ei,
    const float* __restrict__ w0, const float* __restrict__ w1,
    const float* __restrict__ w2, const float* __restrict__ w3,
    const float* __restrict__ w4, const float* __restrict__ w5,
    ushort* __restrict__ bhi, ushort* __restrict__ blo,
    ushort* __restrict__ ahi, ushort* __restrict__ alo,
    int* __restrict__ counts)
{
  const int gid = blockIdx.x * 256 + threadIdx.x;
  const int gstride = gridDim.x * 256;

  // weights -> bf16 hi/lo planes (rows: Wl then Wr per layer)
  for (int g = gid; g < 6 * 16384; g += gstride) {
    int mat = g >> 14;
    int r = g & 16383;
    const float* s = w0;
    if (mat == 1) s = w1; else if (mat == 2) s = w2; else if (mat == 3) s = w3;
    else if (mat == 4) s = w4; else if (mat == 5) s = w5;
    ushort h, l;
    bsplit(s[r], h, l);
    int o = (mat >> 1) * 32768 + (mat & 1) * 16384 + r;
    bhi[o] = h;
    blo[o] = l;
  }
  // x -> bf16 hi/lo planes
  for (int idx = gid; idx < NNODES * 32; idx += gstride) {
    float4 v = ((const float4*)x)[idx];
    ushort h0,l0,h1,l1,h2,l2,h3,l3;
    bsplit(v.x, h0, l0); bsplit(v.y, h1, l1);
    bsplit(v.z, h2, l2); bsplit(v.w, h3, l3);
    ushort4 hv = {h0, h1, h2, h3};
    ushort4 lv = {l0, l1, l2, l3};
    ((ushort4*)ahi)[idx] = hv;
    ((ushort4*)alo)[idx] = lv;
  }
  // dst histogram (counts pre-zeroed by memset)
  for (int e = gid; e < NEDGES; e += gstride)
    atomicAdd(&counts[ei[NEDGES + e]], 1);
}

// ------------------------------------------------------------- CSR build
__global__ __launch_bounds__(256) void scan_part(
    const int* __restrict__ counts, int* __restrict__ part,
    int* __restrict__ bsum)
{
  __shared__ int sh[256];
  int t = threadIdx.x;
  int i = blockIdx.x * 256 + t;
  int v = (i < NNODES) ? counts[i] + 1 : 0;   // +1 = self loop slot
  sh[t] = v;
  __syncthreads();
  for (int off = 1; off < 256; off <<= 1) {
    int u = (t >= off) ? sh[t - off] : 0;
    __syncthreads();
    sh[t] += u;
    __syncthreads();
  }
  if (i < NNODES) part[i] = sh[t] - v;
  if (t == 255) bsum[blockIdx.x] = sh[255];
}

__global__ __launch_bounds__(256) void scan_bsums(int* __restrict__ bsum)
{
  __shared__ int sh[256];
  int t = threadIdx.x;
  int v = (t < NBLK) ? bsum[t] : 0;
  sh[t] = v;
  __syncthreads();
  for (int off = 1; off < 256; off <<= 1) {
    int u = (t >= off) ? sh[t - off] : 0;
    __syncthreads();
    sh[t] += u;
    __syncthreads();
  }
  if (t < NBLK) bsum[t] = sh[t] - v;
}

__global__ __launch_bounds__(256) void scan_final(
    const int* __restrict__ part, const int* __restrict__ bsum,
    int* __restrict__ rowptr, int* __restrict__ cursor)
{
  int i = blockIdx.x * 256 + threadIdx.x;
  if (i < NNODES) {
    int r = part[i] + bsum[blockIdx.x];
    rowptr[i] = r;
    cursor[i] = r;
  }
  if (i == 0) rowptr[NNODES] = NEDGES + NNODES;
}

__global__ __launch_bounds__(256) void scatter_kernel(
    const int* __restrict__ ei, int* __restrict__ cursor,
    int* __restrict__ col)
{
  int e = blockIdx.x * 256 + threadIdx.x;
  if (e < NEDGES + NNODES) {
    int s, d;
    if (e < NEDGES) { s = ei[e]; d = ei[NEDGES + e]; }
    else           { s = e - NEDGES; d = s; }   // self loop
    int slot = atomicAdd(&cursor[d], 1);
    col[slot] = s;
  }
}

// ------------------------------------------------- MFMA split-bf16 dual GEMM
// xl[m][n] = sum_k h[m][k] Wl[n][k]; xr likewise; one M x 256 GEMM with
// B = [Wl ; Wr], C = Ah.Bh + Ah.Bl + Al.Bh (fp32 acc, Al.Bl dropped).
__global__ __launch_bounds__(256) void gemm_mfma(
    const ushort* __restrict__ ahi, const ushort* __restrict__ alo,
    const ushort* __restrict__ bhi, const ushort* __restrict__ blo,
    float* __restrict__ xl, float* __restrict__ xr)
{
  const int wave = threadIdx.x >> 6;
  const int lane = threadIdx.x & 63;
  const int l16  = lane & 15;
  const int kq   = lane >> 4;              // 0..3
  const int m0   = blockIdx.x * 64;

  ffrag acc[4][4];
#pragma unroll
  for (int mt = 0; mt < 4; ++mt)
#pragma unroll
    for (int nt = 0; nt < 4; ++nt)
      acc[mt][nt] = (ffrag){0.f, 0.f, 0.f, 0.f};

#pragma unroll
  for (int kb = 0; kb < 4; ++kb) {
    const int k0 = kb * 32 + kq * 8;
    bfrag ah[4], al[4], bh[4], bl[4];
#pragma unroll
    for (int mt = 0; mt < 4; ++mt) {
      int m = m0 + mt * 16 + l16;          // < NPAD (planes padded)
      ah[mt] = *(const bfrag*)&ahi[m * 128 + k0];
      al[mt] = *(const bfrag*)&alo[m * 128 + k0];
    }
#pragma unroll
    for (int nt = 0; nt < 4; ++nt) {
      int n = wave * 64 + nt * 16 + l16;   // 0..255
      bh[nt] = *(const bfrag*)&bhi[n * 128 + k0];
      bl[nt] = *(const bfrag*)&blo[n * 128 + k0];
    }
#pragma unroll
    for (int mt = 0; mt < 4; ++mt)
#pragma unroll
      for (int nt = 0; nt < 4; ++nt) {
        acc[mt][nt] = __builtin_amdgcn_mfma_f32_16x16x32_bf16(
            ah[mt], bh[nt], acc[mt][nt], 0, 0, 0);
        acc[mt][nt] = __builtin_amdgcn_mfma_f32_16x16x32_bf16(
            ah[mt], bl[nt], acc[mt][nt], 0, 0, 0);
        acc[mt][nt] = __builtin_amdgcn_mfma_f32_16x16x32_bf16(
            al[mt], bh[nt], acc[mt][nt], 0, 0, 0);
      }
  }

#pragma unroll
  for (int mt = 0; mt < 4; ++mt) {
    int mb = m0 + mt * 16 + kq * 4;
#pragma unroll
    for (int nt = 0; nt < 4; ++nt) {
      int ng = wave * 64 + nt * 16 + l16;
      float* dst = (ng < 128) ? xl : xr;
      int n = ng & 127;
#pragma unroll
      for (int r = 0; r < 4; ++r) {
        int m = mb + r;
        if (m < NNODES) dst[m * 128 + n] = acc[mt][nt][r];
      }
    }
  }
}

// ---------------------------------------- fused attention + aggregate + GELU
// One wave per dst node, two 32-lane halves, each half 2 edges/iter with
// inline masking. Logit algebra: leaky(t)=0.6t+0.4|t|; per-dst 0.6*att.xr
// shift cancels in softmax -> q = 0.4L*att.|v+xr| + 0.6L*att.v in base-2.
// Deferred-max: single per-half reference m2, rescale only if q > m2+86.
__global__ __launch_bounds__(256) void agg_kernel(
    const int* __restrict__ rowptr, const int* __restrict__ col,
    const float* __restrict__ xl, const float* __restrict__ xr,
    const float* __restrict__ att, const float* __restrict__ bias,
    float* __restrict__ hout, ushort* __restrict__ ahi,
    ushort* __restrict__ alo, int last)
{
  const int tid  = threadIdx.x;
  const int lane = tid & 63;
  const int half = lane >> 5;
  const int l32  = lane & 31;
  const int d    = blockIdx.x * 4 + (tid >> 6);

  const float4* xl4 = (const float4*)xl;
  float4 xrv = ((const float4*)xr)[d * 32 + l32];
  float4 avr = ((const float4*)att)[l32];
  const float CA = 0.4f * 1.4426950408889634f;
  const float CP = 0.6f * 1.4426950408889634f;
  float4 avA, avP;
  avA.x = avr.x * CA; avA.y = avr.y * CA; avA.z = avr.z * CA; avA.w = avr.w * CA;
  avP.x = avr.x * CP; avP.y = avr.y * CP; avP.z = avr.z * CP; avP.w = avr.w * CP;
  int beg = rowptr[d], end = rowptr[d + 1];

  float m2 = -1e30f;                      // finite sentinel (not -inf)
  float dn0 = 0.f, dn1 = 0.f;
  float4 a0 = {0.f,0.f,0.f,0.f}, a1 = {0.f,0.f,0.f,0.f};

  for (int k0 = beg + 2 * half; k0 < end; k0 += 4) {
    int kb = k0 + 1;                      // k0 always valid; kb maybe not
    bool vb = kb < end;
    int ca = col[k0];
    int cb = col[vb ? kb : beg];
    float4 va = xl4[ca * 32 + l32];
    float4 vB = xl4[cb * 32 + l32];

    float4 ta, tb;
    ta.x = va.x + xrv.x; ta.y = va.y + xrv.y; ta.z = va.z + xrv.z; ta.w = va.w + xrv.w;
    tb.x = vB.x + xrv.x; tb.y = vB.y + xrv.y; tb.z = vB.z + xrv.z; tb.w = vB.w + xrv.w;

    float qa = fmaf(avA.x, fabsf(ta.x), avP.x * va.x);
    qa = fmaf(avA.y, fabsf(ta.y), fmaf(avP.y, va.y, qa));
    qa = fmaf(avA.z, fabsf(ta.z), fmaf(avP.z, va.z, qa));
    qa = fmaf(avA.w, fabsf(ta.w), fmaf(avP.w, va.w, qa));
    float qb = fmaf(avA.x, fabsf(tb.x), avP.x * vB.x);
    qb = fmaf(avA.y, fabsf(tb.y), fmaf(avP.y, vB.y, qb));
    qb = fmaf(avA.z, fabsf(tb.z), fmaf(avP.z, vB.z, qb));
    qb = fmaf(avA.w, fabsf(tb.w), fmaf(avP.w, vB.w, qb));
#pragma unroll
    for (int off = 16; off > 0; off >>= 1) {   // 2 independent chains
      qa += __shfl_xor(qa, off, 64);
      qb += __shfl_xor(qb, off, 64);
    }
    if (!vb) qb = -FLT_MAX;               // exp2(qb-m2) -> 0
    float qm = fmaxf(qa, qb);
    if (qm > m2 + 86.f) {                 // first iter + rare outliers
      float sc = exp2f(m2 - qm);          // m2=-1e30 -> 0: zeroes zeros
      dn0 *= sc; dn1 *= sc;
      a0.x *= sc; a0.y *= sc; a0.z *= sc; a0.w *= sc;
      a1.x *= sc; a1.y *= sc; a1.z *= sc; a1.w *= sc;
      m2 = qm;
    }
    float wa = exp2f(qa - m2);
    float wb = exp2f(qb - m2);
    dn0 += wa; dn1 += wb;
    a0.x = fmaf(wa, va.x, a0.x); a0.y = fmaf(wa, va.y, a0.y);
    a0.z = fmaf(wa, va.z, a0.z); a0.w = fmaf(wa, va.w, a0.w);
    a1.x = fmaf(wb, vB.x, a1.x); a1.y = fmaf(wb, vB.y, a1.y);
    a1.z = fmaf(wb, vB.z, a1.z); a1.w = fmaf(wb, vB.w, a1.w);
  }

  // intra-half states share m2 -> plain adds
  float dn = dn0 + dn1;
  float4 ac;
  ac.x = a0.x + a1.x; ac.y = a0.y + a1.y;
  ac.z = a0.z + a1.z; ac.w = a0.w + a1.w;

  // merge across halves; empty half has m2=-1e30 -> weight 0
  float Mo  = __shfl_xor(m2, 32, 64);
  float dno = __shfl_xor(dn, 32, 64);
  float aox = __shfl_xor(ac.x, 32, 64);
  float aoy = __shfl_xor(ac.y, 32, 64);
  float aoz = __shfl_xor(ac.z, 32, 64);
  float aow = __shfl_xor(ac.w, 32, 64);
  float M  = fmaxf(m2, Mo);
  float eA = exp2f(m2 - M), eB = exp2f(Mo - M);
  float den = dn * eA + dno * eB;
  float inv = 1.f / den;
  float4 bi = ((const float4*)bias)[l32];
  float o0 = fmaf((ac.x * eA + aox * eB), inv, bi.x);
  float o1 = fmaf((ac.y * eA + aoy * eB), inv, bi.y);
  float o2 = fmaf((ac.z * eA + aoz * eB), inv, bi.z);
  float o3 = fmaf((ac.w * eA + aow * eB), inv, bi.w);
  o0 = 0.5f * o0 * (1.f + erff(o0 * 0.70710678118654752f));
  o1 = 0.5f * o1 * (1.f + erff(o1 * 0.70710678118654752f));
  o2 = 0.5f * o2 * (1.f + erff(o2 * 0.70710678118654752f));
  o3 = 0.5f * o3 * (1.f + erff(o3 * 0.70710678118654752f));
  if (half == 0) {
    if (last) {
      ((float4*)hout)[d * 32 + l32] = make_float4(o0, o1, o2, o3);
    } else {
      ushort h0,l0,h1,l1,h2,l2,h3,l3;
      bsplit(o0, h0, l0); bsplit(o1, h1, l1);
      bsplit(o2, h2, l2); bsplit(o3, h3, l3);
      ushort4 hv = {h0, h1, h2, h3};
      ushort4 lv = {l0, l1, l2, l3};
      ((ushort4*)ahi)[d * 32 + l32] = hv;
      ((ushort4*)alo)[d * 32 + l32] = lv;
    }
  }
}

// ------------------------------------------------------------------ launch
extern "C" void kernel_launch(void* const* d_in, const int* in_sizes, int n_in,
                              void* d_out, int out_size, void* d_ws, size_t ws_size,
                              hipStream_t stream)
{
  const float* x = (const float*)d_in[0];
  const int* ei = (const int*)d_in[1];     // int inputs arrive as int32
  const float *Wl[3], *Wr[3], *attv[3], *bv[3];
  for (int l = 0; l < 3; ++l) {
    Wl[l]   = (const float*)d_in[2 + 4 * l];
    Wr[l]   = (const float*)d_in[3 + 4 * l];
    attv[l] = (const float*)d_in[4 + 4 * l];
    bv[l]   = (const float*)d_in[5 + 4 * l];
  }

  char* base = (char*)d_ws;
  size_t off = 0;
  auto alloc = [&](size_t bytes) -> char* {
    char* p = base + off;
    off += (bytes + 255) & ~(size_t)255;
    return p;
  };
  int* counts  = (int*)alloc((size_t)NNODES * 4);
  ushort* ahi  = (ushort*)alloc((size_t)NPAD * 128 * 2);    // 12.8 MB
  ushort* alo  = (ushort*)alloc((size_t)NPAD * 128 * 2);
  ushort* bhi  = (ushort*)alloc((size_t)3 * 256 * 128 * 2); // 196 KB
  ushort* blo  = (ushort*)alloc((size_t)3 * 256 * 128 * 2);
  float* xl    = (float*)alloc((size_t)NNODES * 128 * 4);   // 25.6 MB
  int* rowptr  = (int*)alloc((size_t)(NNODES + 1) * 4);
  int* cursor  = (int*)alloc((size_t)NNODES * 4);
  int* part    = (int*)alloc((size_t)(NBLK * 256) * 4);
  int* bsum    = (int*)alloc((size_t)256 * 4);
  int* col     = (int*)alloc((size_t)(NEDGES + NNODES) * 4);
  float* xr    = (float*)d_out;   // aliased: agg wave reads its xr row before
                                  // writing the same row; no cross-row hazard.
  (void)ws_size; (void)in_sizes; (void)n_in; (void)out_size;

  (void)hipMemsetAsync(counts, 0, (size_t)NNODES * 4, stream);
  prep0_kernel<<<1024, 256, 0, stream>>>(
      x, ei, Wl[0], Wr[0], Wl[1], Wr[1], Wl[2], Wr[2],
      bhi, blo, ahi, alo, counts);
  scan_part<<<NBLK, 256, 0, stream>>>(counts, part, bsum);
  scan_bsums<<<1, 256, 0, stream>>>(bsum);
  scan_final<<<NBLK, 256, 0, stream>>>(part, bsum, rowptr, cursor);
  scatter_kernel<<<(NEDGES + NNODES + 255) / 256, 256, 0, stream>>>(ei, cursor, col);

  for (int l = 0; l < 3; ++l) {
    gemm_mfma<<<NPAD / 64, 256, 0, stream>>>(
        ahi, alo, bhi + (size_t)l * 32768, blo + (size_t)l * 32768, xl, xr);
    agg_kernel<<<NNODES / 4, 256, 0, stream>>>(
        rowptr, col, xl, xr, attv[l], bv[l], (float*)d_out, ahi, alo,
        (l == 2) ? 1 : 0);
  }
}